// Round 9
// baseline (11.577 us; speedup 1.0000x reference)
//
#include <hip/hip_runtime.h>

// out[b,c,m] = max_n x[b,c,n] * Bt[m,n],  Bt binary {0,1}, ~3 ones per row of 2048.
// Exact sparse evaluation, TWO waves per row (half-row each), 8 waves / 512
// threads per block -> 4 rows per block, 1024 blocks = 4 blocks/CU = 32
// waves/CU (max TLP; halves per-wave latency exposure vs one-wave-per-row):
//   - each wave loads its 4 KB half-row as 4 float4 per lane (coalesced)
//   - one combined ballot per 256-element chunk skips empty chunks
//   - non-empty: 4 per-component ballots; gather columns derive from the
//     wave-uniform masks (no data shuffles); lanes 0..31 fmax-gather x
//   - partial (mx, cnt) per half-row staged in LDS; 128 threads combine the
//     two halves and store transposed (16 B runs per channel)
//   - clamp at 0 iff total cnt < 2048 (a zero term exists in the dense max);
//     all-ones row (cnt==2048) keeps the raw max — exact for any input.
// Every output element has exactly one writer -> plain stores, 1 dispatch.

#define HG_N_IN   2048
#define HG_N_OUT  4096
#define HG_BC     32      // BATCH * FEAT = 2*16
#define HG_RPB    4       // rows per block (8 waves, 2 per row)

typedef float nf4 __attribute__((ext_vector_type(4)));

__global__ __launch_bounds__(512) void hg_rowmax(const nf4* __restrict__ Bt4,
                                                 const float* __restrict__ x,
                                                 float* __restrict__ out) {
    __shared__ float pmx[8][HG_BC + 1];
    __shared__ int   pcnt[8];
    const int w    = threadIdx.x >> 6;           // wave 0..7
    const int lane = threadIdx.x & 63;
    const int rw   = w >> 1;                     // row within block 0..3
    const int h    = w & 1;                      // half of the row 0/1
    const int m0   = blockIdx.x * HG_RPB;
    const int m    = m0 + rw;

    const nf4* half = Bt4 + (size_t)m * (HG_N_IN / 4) + (h << 8);
    nf4 v[4];
    #pragma unroll
    for (int i = 0; i < 4; ++i) v[i] = half[lane + (i << 6)];

    const float* xr = x + (size_t)(lane & (HG_BC - 1)) * HG_N_IN;
    float mx = -INFINITY;
    int cnt = 0;

    #pragma unroll
    for (int i = 0; i < 4; ++i) {
        const int f0 = (v[i].x != 0.0f), f1 = (v[i].y != 0.0f);
        const int f2 = (v[i].z != 0.0f), f3 = (v[i].w != 0.0f);
        unsigned long long any = __ballot((f0 | f1 | f2 | f3) != 0);
        if (any == 0ull) continue;               // wave-uniform skip
        unsigned long long bm[4];
        bm[0] = __ballot(f0); bm[1] = __ballot(f1);
        bm[2] = __ballot(f2); bm[3] = __ballot(f3);
        #pragma unroll
        for (int j = 0; j < 4; ++j) {
            unsigned long long b = bm[j];
            while (b) {
                int s = __ffsll(b) - 1;
                b &= b - 1;
                ++cnt;                           // wave-uniform partial count
                int n = (h << 10) + ((((i << 6) + s)) << 2) + j;
                if (lane < HG_BC) mx = fmaxf(mx, xr[n]);
            }
        }
    }

    if (lane < HG_BC) pmx[w][lane] = mx;
    if (lane == 0)    pcnt[w] = cnt;
    __syncthreads();

    // combine halves + transposed store: 128 threads = 32 ch x 4 rows
    const int t = threadIdx.x;
    if (t < HG_BC * HG_RPB) {
        const int ch = t >> 2;                   // 0..31
        const int dr = t & (HG_RPB - 1);         // 0..3
        float mm = fmaxf(pmx[dr * 2][ch], pmx[dr * 2 + 1][ch]);
        int   c  = pcnt[dr * 2] + pcnt[dr * 2 + 1];
        out[(size_t)ch * HG_N_OUT + m0 + dr] = (c == HG_N_IN) ? mm : fmaxf(mm, 0.0f);
    }
}

extern "C" void kernel_launch(void* const* d_in, const int* in_sizes, int n_in,
                              void* d_out, int out_size, void* d_ws, size_t ws_size,
                              hipStream_t stream) {
    const float* x  = (const float*)d_in[0];     // [2,16,2048] f32
    const nf4* Bt4  = (const nf4*)d_in[1];       // [4096,2048] f32 as float4
    float* out = (float*)d_out;                  // [2,16,4096] f32

    // 2 waves per row, 4 rows per 512-thread block -> 1024 blocks (4/CU)
    hg_rowmax<<<HG_N_OUT / HG_RPB, 512, 0, stream>>>(Bt4, x, out);
}